// Round 1
// baseline (1048.105 us; speedup 1.0000x reference)
//
#include <hip/hip_runtime.h>
#include <cstdint>
#include <cstddef>

// Problem constants (fixed by the reference)
#define HW    16384
#define CCH   256
#define WID   128
#define NB    8
#define NSEL  500
#define NPAD  512

// ---------- helpers ----------
__device__ __forceinline__ unsigned key_of(float f) {
  // monotone float->uint map (larger float -> larger uint); logits are finite
  unsigned u = __float_as_uint(f);
  return (u & 0x80000000u) ? ~u : (u | 0x80000000u);
}

// ---------- K1: saliency logits (sigmoid/bias skipped: monotone) ----------
__global__ __launch_bounds__(256) void score_kernel(const float* __restrict__ x,
                                                    const float* __restrict__ w,
                                                    float* __restrict__ logits) {
  __shared__ float ws[CCH];
  int tid = threadIdx.x;
  ws[tid] = w[tid];
  __syncthreads();
  int pix = blockIdx.x * 256 + tid;            // 0 .. B*HW-1
  int b = pix >> 14, p = pix & (HW - 1);
  const float* xp = x + ((size_t)b << 22) + p; // b*C*HW
  float acc = 0.f;
#pragma unroll 16
  for (int c = 0; c < CCH; c++) acc += xp[(size_t)c * HW] * ws[c];
  logits[pix] = acc;
}

// ---------- K2: per-batch top-500 via 8-bit radix select; builds map ----------
__global__ __launch_bounds__(256) void topk_kernel(const float* __restrict__ logits,
                                                   int* __restrict__ idx_out,
                                                   int* __restrict__ map) {
  int b = blockIdx.x, tid = threadIdx.x;
  const float* lg = logits + (size_t)b * HW;
  __shared__ unsigned hist[256];
  __shared__ unsigned scan[256];
  __shared__ unsigned bc_prefix;
  __shared__ int bc_want;
  __shared__ int cnt;

  for (int p = tid; p < HW; p += 256) map[(size_t)b * HW + p] = -1;

  unsigned prefix = 0;
  int want = NSEL;
  for (int shift = 24; shift >= 0; shift -= 8) {
    hist[tid] = 0;
    __syncthreads();
    for (int p = tid; p < HW; p += 256) {
      unsigned u = key_of(lg[p]);
      bool m = (shift == 24) || ((u >> (shift + 8)) == (prefix >> (shift + 8)));
      if (m) atomicAdd(&hist[(u >> shift) & 255u], 1u);
    }
    __syncthreads();
    if (tid == 0) {
      int d = 256;
      unsigned cum = 0;
      while ((int)cum < want) { d--; cum += hist[d]; }  // total >= want guaranteed
      bc_prefix = prefix | ((unsigned)d << shift);
      bc_want = want - (int)(cum - hist[d]);
    }
    __syncthreads();
    prefix = bc_prefix;
    want = bc_want;
    __syncthreads();
  }
  unsigned thr = prefix;  // exact key of boundary element; `want` ties to take (lowest index)

  // index-ordered tie selection: each thread owns 64 consecutive indices
  int tstart = tid * (HW / 256);
  int local = 0;
  for (int p = tstart; p < tstart + 64; p++)
    if (key_of(lg[p]) == thr) local++;
  scan[tid] = (unsigned)local;
  if (tid == 0) cnt = 0;
  __syncthreads();
  for (int o = 1; o < 256; o <<= 1) {  // Hillis-Steele inclusive scan
    unsigned v = (tid >= o) ? scan[tid - o] : 0u;
    __syncthreads();
    scan[tid] += v;
    __syncthreads();
  }
  int rank = (int)scan[tid] - local;
  for (int p = tstart; p < tstart + 64; p++) {
    unsigned u = key_of(lg[p]);
    bool take = (u > thr);
    if (u == thr) { if (rank < want) take = true; rank++; }
    if (take) {
      int s = atomicAdd(&cnt, 1);
      idx_out[b * NPAD + s] = p;
      map[(size_t)b * HW + p] = s;
    }
  }
}

// ---------- K3: gather 7x7 patches (exact point-weight form) + mean/max pool ----------
__global__ __launch_bounds__(256) void gather_kernel(const float* __restrict__ xm,
                                                     const float* __restrict__ xa,
                                                     const int* __restrict__ idx,
                                                     float* __restrict__ vmain,
                                                     float* __restrict__ vaux) {
  int i = blockIdx.x, b = blockIdx.y, c = threadIdx.x;
  size_t obase = ((size_t)b * NPAD + i) * CCH + c;
  if (i >= NSEL) { vmain[obase] = 0.f; vaux[obase] = 0.f; return; }
  int p = idx[b * NPAD + i];
  int iy = p >> 7, ix = p & (WID - 1);
  float wx[7], wy[7];
  int xc[7], yc[7];
#pragma unroll
  for (int d = 0; d < 7; d++) {
    int t = ix + d - 3;
    bool in = (t >= 0) && (t < WID);
    xc[d] = in ? t : (t < 0 ? 0 : WID - 1);
    wx[d] = in ? 1.f : 0.5f;
    t = iy + d - 3;
    in = (t >= 0) && (t < WID);
    yc[d] = in ? t : (t < 0 ? 0 : WID - 1);
    wy[d] = in ? 1.f : 0.5f;
  }
  const float* pm = xm + ((size_t)(b * CCH + c)) * HW;
  const float* pa = xa + ((size_t)(b * CCH + c)) * HW;
  float sm = 0.f, sa = 0.f, mm = -INFINITY, ma = -INFINITY;
#pragma unroll
  for (int dy = 0; dy < 7; dy++) {
    int rb = yc[dy] * WID;
    float wyd = wy[dy];
#pragma unroll
    for (int dx = 0; dx < 7; dx++) {
      float w = wyd * wx[dx];
      float vm = pm[rb + xc[dx]] * w;
      float va = pa[rb + xc[dx]] * w;
      sm += vm; sa += va;
      mm = fmaxf(mm, vm); ma = fmaxf(ma, va);
    }
  }
  const float inv49 = 1.f / 49.f;
  vmain[obase] = 0.5f * (sm * inv49 + mm);
  vaux[obase]  = 0.5f * (sa * inv49 + ma);
}

// ---------- tiled fp32 GEMM: C[b] = A[b](MxK) * B(KxN)  ----------
// BT: B stored transposed (NxK). BSHARED: B not batched.
// EPI 0: plain store; 1: *0.0625; 2: +bias[col], store transposed [b][N][M]
template <int M, int N, int K, bool BT, bool BSHARED, int EPI>
__global__ __launch_bounds__(256) void gemm_kernel(const float* __restrict__ A,
                                                   const float* __restrict__ B,
                                                   float* __restrict__ C,
                                                   const float* __restrict__ bias) {
  constexpr int BM = 64, BN = 64, BK = 16;
  __shared__ float As[BM][BK + 1];
  __shared__ float Bs[BK][BN + 1];
  int tid = threadIdx.x;
  int bx = blockIdx.x, by = blockIdx.y, b = blockIdx.z;
  const float* Ab = A + (size_t)b * M * K;
  const float* Bb = BSHARED ? B : (B + (size_t)b * ((size_t)K * N));
  int tx = tid & 15, ty = tid >> 4;
  float acc[4][4] = {};
  int ar = tid >> 2, ac4 = (tid & 3) * 4;
  int br = tid >> 4, bc4 = (tid & 15) * 4;

  for (int k0 = 0; k0 < K; k0 += BK) {
    const float4 av = *(const float4*)&Ab[(size_t)(by * BM + ar) * K + k0 + ac4];
    As[ar][ac4 + 0] = av.x; As[ar][ac4 + 1] = av.y;
    As[ar][ac4 + 2] = av.z; As[ar][ac4 + 3] = av.w;
    if (!BT) {
      const float4 bv = *(const float4*)&Bb[(size_t)(k0 + br) * N + bx * BN + bc4];
      Bs[br][bc4 + 0] = bv.x; Bs[br][bc4 + 1] = bv.y;
      Bs[br][bc4 + 2] = bv.z; Bs[br][bc4 + 3] = bv.w;
    } else {
      const float4 bv = *(const float4*)&Bb[(size_t)(bx * BN + ar) * K + k0 + ac4];
      Bs[ac4 + 0][ar] = bv.x; Bs[ac4 + 1][ar] = bv.y;
      Bs[ac4 + 2][ar] = bv.z; Bs[ac4 + 3][ar] = bv.w;
    }
    __syncthreads();
#pragma unroll
    for (int kk = 0; kk < BK; kk++) {
      float a[4], bb[4];
#pragma unroll
      for (int r = 0; r < 4; r++) a[r] = As[ty * 4 + r][kk];
#pragma unroll
      for (int s = 0; s < 4; s++) bb[s] = Bs[kk][tx * 4 + s];
#pragma unroll
      for (int r = 0; r < 4; r++)
#pragma unroll
        for (int s = 0; s < 4; s++) acc[r][s] += a[r] * bb[s];
    }
    __syncthreads();
  }
  if (EPI == 2) {
#pragma unroll
    for (int s = 0; s < 4; s++) {
      int col = bx * BN + tx * 4 + s;
      float bv = bias[col];
#pragma unroll
      for (int r = 0; r < 4; r++) {
        int row = by * BM + ty * 4 + r;
        C[((size_t)b * N + col) * M + row] = acc[r][s] + bv;
      }
    }
  } else {
    float scale = (EPI == 1) ? 0.0625f : 1.f;  // 1/sqrt(256)
#pragma unroll
    for (int r = 0; r < 4; r++) {
      int row = by * BM + ty * 4 + r;
#pragma unroll
      for (int s = 0; s < 4; s++) {
        int col = bx * BN + tx * 4 + s;
        C[((size_t)b * M + row) * N + col] = acc[r][s] * scale;
      }
    }
  }
}

// ---------- softmax over j (masked to j<NSEL), in place ----------
__global__ __launch_bounds__(256) void softmax_kernel(float* __restrict__ sim) {
  int i = blockIdx.x, b = blockIdx.y, tid = threadIdx.x;
  float* row = sim + ((size_t)b * NPAD + i) * NPAD;
  float v0 = (tid < NSEL) ? row[tid] : -INFINITY;
  int j1 = tid + 256;
  float v1 = (j1 < NSEL) ? row[j1] : -INFINITY;
  float m = fmaxf(v0, v1);
  for (int o = 32; o; o >>= 1) m = fmaxf(m, __shfl_down(m, o));
  __shared__ float red[4];
  __shared__ float bm, bs;
  int wave = tid >> 6, lane = tid & 63;
  if (lane == 0) red[wave] = m;
  __syncthreads();
  if (tid == 0) bm = fmaxf(fmaxf(red[0], red[1]), fmaxf(red[2], red[3]));
  __syncthreads();
  m = bm;
  float e0 = (tid < NSEL) ? expf(v0 - m) : 0.f;
  float e1 = (j1 < NSEL) ? expf(v1 - m) : 0.f;
  float s = e0 + e1;
  for (int o = 32; o; o >>= 1) s += __shfl_down(s, o);
  if (lane == 0) red[wave] = s;
  __syncthreads();
  if (tid == 0) bs = 1.f / (red[0] + red[1] + red[2] + red[3]);
  __syncthreads();
  row[tid] = e0 * bs;
  row[j1] = e1 * bs;
}

// ---------- gated-fusion MLP; writes v_fused in place over v_main ----------
__global__ __launch_bounds__(256) void mlp_kernel(const float* __restrict__ vmain,
                                                  const float* __restrict__ vhat,
                                                  const float* __restrict__ fc1w,
                                                  const float* __restrict__ fc1b,
                                                  const float* __restrict__ fc2w,
                                                  const float* __restrict__ fc2b,
                                                  float* __restrict__ vfused) {
  int i = blockIdx.x, b = blockIdx.y, c = threadIdx.x;
  size_t base = ((size_t)b * NPAD + i) * CCH + c;
  float vm = vmain[base], vh = vhat[base], vd = vm - vh;
  const float* w0 = fc1w + (size_t)c * 16;
  const float* w1 = fc1w + (size_t)(256 + c) * 16;
  const float* w2 = fc1w + (size_t)(512 + c) * 16;
  float ph[16];
#pragma unroll
  for (int k = 0; k < 16; k++) ph[k] = vm * w0[k] + vh * w1[k] + vd * w2[k];
#pragma unroll
  for (int o = 32; o; o >>= 1)
#pragma unroll
    for (int k = 0; k < 16; k++) ph[k] += __shfl_down(ph[k], o);
  __shared__ float red[4][16];
  __shared__ float hsh[16];
  int wave = c >> 6, lane = c & 63;
  if (lane == 0)
#pragma unroll
    for (int k = 0; k < 16; k++) red[wave][k] = ph[k];
  __syncthreads();
  if (c < 16) {
    float s = red[0][c] + red[1][c] + red[2][c] + red[3][c] + fc1b[c];
    hsh[c] = fmaxf(s, 0.f);
  }
  __syncthreads();
  float g = fc2b[c];
#pragma unroll
  for (int k = 0; k < 16; k++) g += hsh[k] * fc2w[k * 256 + c];
  g = 1.f / (1.f + expf(-g));
  vfused[base] = vm + g * vd;
}

// ---------- K5: out = x_main + dense-map lookup of v_injT ----------
__global__ __launch_bounds__(256) void final_kernel(const float* __restrict__ x,
                                                    const int* __restrict__ map,
                                                    const float* __restrict__ vinjT,
                                                    float* __restrict__ out) {
  int gid = blockIdx.x * 256 + threadIdx.x;  // B*C*HW/4 threads
  int p4 = gid & 4095;
  int c = (gid >> 12) & 255;
  int b = gid >> 20;
  size_t xoff = (((size_t)(b * 256 + c)) << 14) + ((size_t)p4 << 2);
  float4 xv = *(const float4*)(x + xoff);
  const int4 mv = *(const int4*)(map + ((size_t)b << 14) + (p4 << 2));
  const float* vt = vinjT + ((size_t)(b * 256 + c) << 9);
  if (mv.x >= 0) xv.x += vt[mv.x];
  if (mv.y >= 0) xv.y += vt[mv.y];
  if (mv.z >= 0) xv.z += vt[mv.z];
  if (mv.w >= 0) xv.w += vt[mv.w];
  *(float4*)(out + xoff) = xv;
}

extern "C" void kernel_launch(void* const* d_in, const int* in_sizes, int n_in,
                              void* d_out, int out_size, void* d_ws, size_t ws_size,
                              hipStream_t stream) {
  const float* x_main   = (const float*)d_in[0];
  const float* x_aux    = (const float*)d_in[1];
  const float* scorer_w = (const float*)d_in[2];
  // d_in[3] scorer_b: constant shift, irrelevant to top-k set -> unused
  const float* fc1_w = (const float*)d_in[4];
  const float* fc1_b = (const float*)d_in[5];
  const float* fc2_w = (const float*)d_in[6];
  const float* fc2_b = (const float*)d_in[7];
  const float* proj_w = (const float*)d_in[8];
  const float* proj_b = (const float*)d_in[9];
  // d_in[10] n == 500 (fixed)
  (void)in_sizes; (void)n_in; (void)out_size; (void)ws_size;

  float* ws = (float*)d_ws;
  // workspace layout (floats); ~21 MB total, buffers reused downstream
  float* logits = ws;                      // 131072
  int*   idx    = (int*)(ws + 131072);     // 4096
  int*   map    = (int*)(ws + 135168);     // 131072
  float* vmain  = ws + 266240;             // 1048576 (v_fused in place)
  float* vaux   = ws + 1314816;            // 1048576
  float* vhat   = ws + 2363392;            // 1048576 (v_injT reuses this)
  float* sim    = ws + 3411968;            // 2097152
  float* vinjT  = vhat;
  float* out = (float*)d_out;

  score_kernel<<<512, 256, 0, stream>>>(x_main, scorer_w, logits);
  topk_kernel<<<NB, 256, 0, stream>>>(logits, idx, map);
  gather_kernel<<<dim3(NPAD, NB), 256, 0, stream>>>(x_main, x_aux, idx, vmain, vaux);
  // sim = v_main @ v_aux^T / 16
  gemm_kernel<NPAD, NPAD, CCH, true, false, 1>
      <<<dim3(8, 8, NB), 256, 0, stream>>>(vmain, vaux, sim, nullptr);
  softmax_kernel<<<dim3(NPAD, NB), 256, 0, stream>>>(sim);
  // v_hat = attn @ v_aux
  gemm_kernel<NPAD, CCH, NPAD, false, false, 0>
      <<<dim3(4, 8, NB), 256, 0, stream>>>(sim, vaux, vhat, nullptr);
  mlp_kernel<<<dim3(NPAD, NB), 256, 0, stream>>>(vmain, vhat, fc1_w, fc1_b,
                                                 fc2_w, fc2_b, vmain);
  // v_injT[b][c][i] = (v_fused @ proj_w + proj_b)^T
  gemm_kernel<NPAD, CCH, CCH, false, true, 2>
      <<<dim3(4, 8, NB), 256, 0, stream>>>(vmain, proj_w, vinjT, proj_b);
  final_kernel<<<32768, 256, 0, stream>>>(x_main, map, vinjT, out);
}

// Round 2
// 679.056 us; speedup vs baseline: 1.5435x; 1.5435x over previous
//
#include <hip/hip_runtime.h>
#include <cstdint>
#include <cstddef>

// Problem constants (fixed by the reference)
#define HW    16384
#define CCH   256
#define WID   128
#define NB    8
#define NSEL  500
#define NPAD  512

// ---------- helpers ----------
__device__ __forceinline__ unsigned key_of(float f) {
  // monotone float->uint map (larger float -> larger uint); logits are finite
  unsigned u = __float_as_uint(f);
  return (u & 0x80000000u) ? ~u : (u | 0x80000000u);
}

// ---------- K1: saliency logits (sigmoid/bias skipped: monotone) ----------
__global__ __launch_bounds__(256) void score_kernel(const float* __restrict__ x,
                                                    const float* __restrict__ w,
                                                    float* __restrict__ logits) {
  __shared__ float ws[CCH];
  int tid = threadIdx.x;
  ws[tid] = w[tid];
  __syncthreads();
  int pix = blockIdx.x * 256 + tid;            // 0 .. B*HW-1
  int b = pix >> 14, p = pix & (HW - 1);
  const float* xp = x + ((size_t)b << 22) + p; // b*C*HW
  float acc = 0.f;
#pragma unroll 16
  for (int c = 0; c < CCH; c++) acc += xp[(size_t)c * HW] * ws[c];
  logits[pix] = acc;
}

// ---------- K1b: [C,HW] -> [HW,C] tile transpose (per batch) ----------
__global__ __launch_bounds__(256) void transpose_kernel(const float* __restrict__ x,
                                                        float* __restrict__ xt) {
  __shared__ float tile[64][65];
  int b = blockIdx.z;
  int p0 = blockIdx.x * 64;   // pixel tile
  int c0 = blockIdx.y * 64;   // channel tile
  int tid = threadIdx.x;
  int r = tid >> 4, q = tid & 15;
  const float* xb = x + ((size_t)b << 22);
#pragma unroll
  for (int j = 0; j < 4; j++) {
    int c = c0 + r + j * 16;
    float4 v = *(const float4*)&xb[(size_t)c * HW + p0 + q * 4];
    tile[r + j * 16][q * 4 + 0] = v.x;
    tile[r + j * 16][q * 4 + 1] = v.y;
    tile[r + j * 16][q * 4 + 2] = v.z;
    tile[r + j * 16][q * 4 + 3] = v.w;
  }
  __syncthreads();
  float* xtb = xt + (((size_t)b << 14) << 8);  // b*HW*C
#pragma unroll
  for (int j = 0; j < 4; j++) {
    int pl = r + j * 16;
    float4 v;
    v.x = tile[q * 4 + 0][pl];
    v.y = tile[q * 4 + 1][pl];
    v.z = tile[q * 4 + 2][pl];
    v.w = tile[q * 4 + 3][pl];
    *(float4*)&xtb[(size_t)(p0 + pl) * CCH + c0 + q * 4] = v;
  }
}

// ---------- K2: per-batch top-500 via 8-bit radix select; builds map ----------
__global__ __launch_bounds__(256) void topk_kernel(const float* __restrict__ logits,
                                                   int* __restrict__ idx_out,
                                                   int* __restrict__ map) {
  int b = blockIdx.x, tid = threadIdx.x;
  const float* lg = logits + (size_t)b * HW;
  __shared__ unsigned hist[256];
  __shared__ unsigned scan[256];
  __shared__ unsigned bc_prefix;
  __shared__ int bc_want;
  __shared__ int cnt;

  for (int p = tid; p < HW; p += 256) map[(size_t)b * HW + p] = -1;

  unsigned prefix = 0;
  int want = NSEL;
  for (int shift = 24; shift >= 0; shift -= 8) {
    hist[tid] = 0;
    __syncthreads();
    for (int p = tid; p < HW; p += 256) {
      unsigned u = key_of(lg[p]);
      bool m = (shift == 24) || ((u >> (shift + 8)) == (prefix >> (shift + 8)));
      if (m) atomicAdd(&hist[(u >> shift) & 255u], 1u);
    }
    __syncthreads();
    if (tid == 0) {
      int d = 256;
      unsigned cum = 0;
      while ((int)cum < want) { d--; cum += hist[d]; }  // total >= want guaranteed
      bc_prefix = prefix | ((unsigned)d << shift);
      bc_want = want - (int)(cum - hist[d]);
    }
    __syncthreads();
    prefix = bc_prefix;
    want = bc_want;
    __syncthreads();
  }
  unsigned thr = prefix;  // exact key of boundary element; `want` ties to take (lowest index)

  // index-ordered tie selection: each thread owns 64 consecutive indices
  int tstart = tid * (HW / 256);
  int local = 0;
  for (int p = tstart; p < tstart + 64; p++)
    if (key_of(lg[p]) == thr) local++;
  scan[tid] = (unsigned)local;
  if (tid == 0) cnt = 0;
  __syncthreads();
  for (int o = 1; o < 256; o <<= 1) {  // Hillis-Steele inclusive scan
    unsigned v = (tid >= o) ? scan[tid - o] : 0u;
    __syncthreads();
    scan[tid] += v;
    __syncthreads();
  }
  int rank = (int)scan[tid] - local;
  for (int p = tstart; p < tstart + 64; p++) {
    unsigned u = key_of(lg[p]);
    bool take = (u > thr);
    if (u == thr) { if (rank < want) take = true; rank++; }
    if (take) {
      int s = atomicAdd(&cnt, 1);
      idx_out[b * NPAD + s] = p;
      map[(size_t)b * HW + p] = s;
    }
  }
}

// ---------- shared patch-weight computation ----------
__device__ __forceinline__ void patch_weights(int p, int* xc, int* yc, float* wx, float* wy) {
  int iy = p >> 7, ix = p & (WID - 1);
#pragma unroll
  for (int d = 0; d < 7; d++) {
    int t = ix + d - 3;
    bool in = (t >= 0) && (t < WID);
    xc[d] = in ? t : (t < 0 ? 0 : WID - 1);
    wx[d] = in ? 1.f : 0.5f;
    t = iy + d - 3;
    in = (t >= 0) && (t < WID);
    yc[d] = in ? t : (t < 0 ? 0 : WID - 1);
    wy[d] = in ? 1.f : 0.5f;
  }
}

// ---------- K3 (fast path): gather from transposed [B,HW,C] layout ----------
__global__ __launch_bounds__(256) void gather_t_kernel(const float* __restrict__ xtm,
                                                       const float* __restrict__ xta,
                                                       const int* __restrict__ idx,
                                                       float* __restrict__ vmain,
                                                       float* __restrict__ vaux) {
  int i = blockIdx.x, b = blockIdx.y, c = threadIdx.x;
  size_t obase = ((size_t)b * NPAD + i) * CCH + c;
  if (i >= NSEL) { vmain[obase] = 0.f; vaux[obase] = 0.f; return; }
  int p = idx[b * NPAD + i];
  float wx[7], wy[7];
  int xc[7], yc[7];
  patch_weights(p, xc, yc, wx, wy);
  const float* bm = xtm + ((((size_t)b << 14)) << 8) + c;  // b*HW*C + c
  const float* ba = xta + ((((size_t)b << 14)) << 8) + c;
  float sm = 0.f, sa = 0.f, mm = -INFINITY, ma = -INFINITY;
#pragma unroll
  for (int dy = 0; dy < 7; dy++) {
    int rb = yc[dy] * WID;
    float wyd = wy[dy];
#pragma unroll
    for (int dx = 0; dx < 7; dx++) {
      float w = wyd * wx[dx];
      size_t off = (size_t)(rb + xc[dx]) << 8;  // pixel*C
      float vm = bm[off] * w;
      float va = ba[off] * w;
      sm += vm; sa += va;
      mm = fmaxf(mm, vm); ma = fmaxf(ma, va);
    }
  }
  const float inv49 = 1.f / 49.f;
  vmain[obase] = 0.5f * (sm * inv49 + mm);
  vaux[obase]  = 0.5f * (sa * inv49 + ma);
}

// ---------- K3 (fallback): gather from original [B,C,HW] layout ----------
__global__ __launch_bounds__(256) void gather_kernel(const float* __restrict__ xm,
                                                     const float* __restrict__ xa,
                                                     const int* __restrict__ idx,
                                                     float* __restrict__ vmain,
                                                     float* __restrict__ vaux) {
  int i = blockIdx.x, b = blockIdx.y, c = threadIdx.x;
  size_t obase = ((size_t)b * NPAD + i) * CCH + c;
  if (i >= NSEL) { vmain[obase] = 0.f; vaux[obase] = 0.f; return; }
  int p = idx[b * NPAD + i];
  float wx[7], wy[7];
  int xc[7], yc[7];
  patch_weights(p, xc, yc, wx, wy);
  const float* pm = xm + ((size_t)(b * CCH + c)) * HW;
  const float* pa = xa + ((size_t)(b * CCH + c)) * HW;
  float sm = 0.f, sa = 0.f, mm = -INFINITY, ma = -INFINITY;
#pragma unroll
  for (int dy = 0; dy < 7; dy++) {
    int rb = yc[dy] * WID;
    float wyd = wy[dy];
#pragma unroll
    for (int dx = 0; dx < 7; dx++) {
      float w = wyd * wx[dx];
      float vm = pm[rb + xc[dx]] * w;
      float va = pa[rb + xc[dx]] * w;
      sm += vm; sa += va;
      mm = fmaxf(mm, vm); ma = fmaxf(ma, va);
    }
  }
  const float inv49 = 1.f / 49.f;
  vmain[obase] = 0.5f * (sm * inv49 + mm);
  vaux[obase]  = 0.5f * (sa * inv49 + ma);
}

// ---------- tiled fp32 GEMM: C[b] = A[b](MxK) * B(KxN)  ----------
// BT: B stored transposed (NxK). BSHARED: B not batched.
// EPI 0: plain store; 1: *0.0625; 2: +bias[col], store transposed [b][N][M]
template <int M, int N, int K, bool BT, bool BSHARED, int EPI>
__global__ __launch_bounds__(256) void gemm_kernel(const float* __restrict__ A,
                                                   const float* __restrict__ B,
                                                   float* __restrict__ C,
                                                   const float* __restrict__ bias) {
  constexpr int BM = 64, BN = 64, BK = 16;
  __shared__ float As[BM][BK + 1];
  __shared__ float Bs[BK][BN + 1];
  int tid = threadIdx.x;
  int bx = blockIdx.x, by = blockIdx.y, b = blockIdx.z;
  const float* Ab = A + (size_t)b * M * K;
  const float* Bb = BSHARED ? B : (B + (size_t)b * ((size_t)K * N));
  int tx = tid & 15, ty = tid >> 4;
  float acc[4][4] = {};
  int ar = tid >> 2, ac4 = (tid & 3) * 4;
  int br = tid >> 4, bc4 = (tid & 15) * 4;

  for (int k0 = 0; k0 < K; k0 += BK) {
    const float4 av = *(const float4*)&Ab[(size_t)(by * BM + ar) * K + k0 + ac4];
    As[ar][ac4 + 0] = av.x; As[ar][ac4 + 1] = av.y;
    As[ar][ac4 + 2] = av.z; As[ar][ac4 + 3] = av.w;
    if (!BT) {
      const float4 bv = *(const float4*)&Bb[(size_t)(k0 + br) * N + bx * BN + bc4];
      Bs[br][bc4 + 0] = bv.x; Bs[br][bc4 + 1] = bv.y;
      Bs[br][bc4 + 2] = bv.z; Bs[br][bc4 + 3] = bv.w;
    } else {
      const float4 bv = *(const float4*)&Bb[(size_t)(bx * BN + ar) * K + k0 + ac4];
      Bs[ac4 + 0][ar] = bv.x; Bs[ac4 + 1][ar] = bv.y;
      Bs[ac4 + 2][ar] = bv.z; Bs[ac4 + 3][ar] = bv.w;
    }
    __syncthreads();
#pragma unroll
    for (int kk = 0; kk < BK; kk++) {
      float a[4], bb[4];
#pragma unroll
      for (int r = 0; r < 4; r++) a[r] = As[ty * 4 + r][kk];
#pragma unroll
      for (int s = 0; s < 4; s++) bb[s] = Bs[kk][tx * 4 + s];
#pragma unroll
      for (int r = 0; r < 4; r++)
#pragma unroll
        for (int s = 0; s < 4; s++) acc[r][s] += a[r] * bb[s];
    }
    __syncthreads();
  }
  if (EPI == 2) {
#pragma unroll
    for (int s = 0; s < 4; s++) {
      int col = bx * BN + tx * 4 + s;
      float bv = bias[col];
#pragma unroll
      for (int r = 0; r < 4; r++) {
        int row = by * BM + ty * 4 + r;
        C[((size_t)b * N + col) * M + row] = acc[r][s] + bv;
      }
    }
  } else {
    float scale = (EPI == 1) ? 0.0625f : 1.f;  // 1/sqrt(256)
#pragma unroll
    for (int r = 0; r < 4; r++) {
      int row = by * BM + ty * 4 + r;
#pragma unroll
      for (int s = 0; s < 4; s++) {
        int col = bx * BN + tx * 4 + s;
        C[((size_t)b * M + row) * N + col] = acc[r][s] * scale;
      }
    }
  }
}

// ---------- softmax over j (masked to j<NSEL), in place ----------
__global__ __launch_bounds__(256) void softmax_kernel(float* __restrict__ sim) {
  int i = blockIdx.x, b = blockIdx.y, tid = threadIdx.x;
  float* row = sim + ((size_t)b * NPAD + i) * NPAD;
  float v0 = (tid < NSEL) ? row[tid] : -INFINITY;
  int j1 = tid + 256;
  float v1 = (j1 < NSEL) ? row[j1] : -INFINITY;
  float m = fmaxf(v0, v1);
  for (int o = 32; o; o >>= 1) m = fmaxf(m, __shfl_down(m, o));
  __shared__ float red[4];
  __shared__ float bm, bs;
  int wave = tid >> 6, lane = tid & 63;
  if (lane == 0) red[wave] = m;
  __syncthreads();
  if (tid == 0) bm = fmaxf(fmaxf(red[0], red[1]), fmaxf(red[2], red[3]));
  __syncthreads();
  m = bm;
  float e0 = (tid < NSEL) ? expf(v0 - m) : 0.f;
  float e1 = (j1 < NSEL) ? expf(v1 - m) : 0.f;
  float s = e0 + e1;
  for (int o = 32; o; o >>= 1) s += __shfl_down(s, o);
  if (lane == 0) red[wave] = s;
  __syncthreads();
  if (tid == 0) bs = 1.f / (red[0] + red[1] + red[2] + red[3]);
  __syncthreads();
  row[tid] = e0 * bs;
  row[j1] = e1 * bs;
}

// ---------- gated-fusion MLP; writes v_fused in place over v_main ----------
__global__ __launch_bounds__(256) void mlp_kernel(const float* __restrict__ vmain,
                                                  const float* __restrict__ vhat,
                                                  const float* __restrict__ fc1w,
                                                  const float* __restrict__ fc1b,
                                                  const float* __restrict__ fc2w,
                                                  const float* __restrict__ fc2b,
                                                  float* __restrict__ vfused) {
  int i = blockIdx.x, b = blockIdx.y, c = threadIdx.x;
  size_t base = ((size_t)b * NPAD + i) * CCH + c;
  float vm = vmain[base], vh = vhat[base], vd = vm - vh;
  const float* w0 = fc1w + (size_t)c * 16;
  const float* w1 = fc1w + (size_t)(256 + c) * 16;
  const float* w2 = fc1w + (size_t)(512 + c) * 16;
  float ph[16];
#pragma unroll
  for (int k = 0; k < 16; k++) ph[k] = vm * w0[k] + vh * w1[k] + vd * w2[k];
#pragma unroll
  for (int o = 32; o; o >>= 1)
#pragma unroll
    for (int k = 0; k < 16; k++) ph[k] += __shfl_down(ph[k], o);
  __shared__ float red[4][16];
  __shared__ float hsh[16];
  int wave = c >> 6, lane = c & 63;
  if (lane == 0)
#pragma unroll
    for (int k = 0; k < 16; k++) red[wave][k] = ph[k];
  __syncthreads();
  if (c < 16) {
    float s = red[0][c] + red[1][c] + red[2][c] + red[3][c] + fc1b[c];
    hsh[c] = fmaxf(s, 0.f);
  }
  __syncthreads();
  float g = fc2b[c];
#pragma unroll
  for (int k = 0; k < 16; k++) g += hsh[k] * fc2w[k * 256 + c];
  g = 1.f / (1.f + expf(-g));
  vfused[base] = vm + g * vd;
}

// ---------- K5: out = x_main + dense-map lookup of v_injT ----------
__global__ __launch_bounds__(256) void final_kernel(const float* __restrict__ x,
                                                    const int* __restrict__ map,
                                                    const float* __restrict__ vinjT,
                                                    float* __restrict__ out) {
  int gid = blockIdx.x * 256 + threadIdx.x;  // B*C*HW/4 threads
  int p4 = gid & 4095;
  int c = (gid >> 12) & 255;
  int b = gid >> 20;
  size_t xoff = (((size_t)(b * 256 + c)) << 14) + ((size_t)p4 << 2);
  float4 xv = *(const float4*)(x + xoff);
  const int4 mv = *(const int4*)(map + ((size_t)b << 14) + (p4 << 2));
  const float* vt = vinjT + ((size_t)(b * 256 + c) << 9);
  if (mv.x >= 0) xv.x += vt[mv.x];
  if (mv.y >= 0) xv.y += vt[mv.y];
  if (mv.z >= 0) xv.z += vt[mv.z];
  if (mv.w >= 0) xv.w += vt[mv.w];
  *(float4*)(out + xoff) = xv;
}

extern "C" void kernel_launch(void* const* d_in, const int* in_sizes, int n_in,
                              void* d_out, int out_size, void* d_ws, size_t ws_size,
                              hipStream_t stream) {
  const float* x_main   = (const float*)d_in[0];
  const float* x_aux    = (const float*)d_in[1];
  const float* scorer_w = (const float*)d_in[2];
  // d_in[3] scorer_b: constant shift, irrelevant to top-k set -> unused
  const float* fc1_w = (const float*)d_in[4];
  const float* fc1_b = (const float*)d_in[5];
  const float* fc2_w = (const float*)d_in[6];
  const float* fc2_b = (const float*)d_in[7];
  const float* proj_w = (const float*)d_in[8];
  const float* proj_b = (const float*)d_in[9];
  // d_in[10] n == 500 (fixed)
  (void)in_sizes; (void)n_in; (void)out_size;

  float* ws = (float*)d_ws;
  // workspace layout (floats)
  float* logits = ws;                      // 131072
  int*   idx    = (int*)(ws + 131072);     // 4096
  int*   map    = (int*)(ws + 135168);     // 131072
  float* vmain  = ws + 266240;             // 1048576 (v_fused in place)
  float* vaux   = ws + 1314816;            // 1048576
  float* vhat   = ws + 2363392;            // 1048576 (v_injT reuses this)
  float* sim    = ws + 3411968;            // 2097152 (ends at 5509120)
  float* xtm    = ws + 5509120;            // 33554432 (transposed x_main, fast path)
  float* xta    = ws + 39063552;           // 33554432 (transposed x_aux)
  float* vinjT  = vhat;
  float* out = (float*)d_out;

  // fast path needs (5509120 + 2*33554432) floats = 290,471,936 bytes
  const bool fast = ws_size >= (size_t)290471936;

  score_kernel<<<512, 256, 0, stream>>>(x_main, scorer_w, logits);
  topk_kernel<<<NB, 256, 0, stream>>>(logits, idx, map);
  if (fast) {
    transpose_kernel<<<dim3(256, 4, NB), 256, 0, stream>>>(x_main, xtm);
    transpose_kernel<<<dim3(256, 4, NB), 256, 0, stream>>>(x_aux, xta);
    gather_t_kernel<<<dim3(NPAD, NB), 256, 0, stream>>>(xtm, xta, idx, vmain, vaux);
  } else {
    gather_kernel<<<dim3(NPAD, NB), 256, 0, stream>>>(x_main, x_aux, idx, vmain, vaux);
  }
  // sim = v_main @ v_aux^T / 16
  gemm_kernel<NPAD, NPAD, CCH, true, false, 1>
      <<<dim3(8, 8, NB), 256, 0, stream>>>(vmain, vaux, sim, nullptr);
  softmax_kernel<<<dim3(NPAD, NB), 256, 0, stream>>>(sim);
  // v_hat = attn @ v_aux
  gemm_kernel<NPAD, CCH, NPAD, false, false, 0>
      <<<dim3(4, 8, NB), 256, 0, stream>>>(sim, vaux, vhat, nullptr);
  mlp_kernel<<<dim3(NPAD, NB), 256, 0, stream>>>(vmain, vhat, fc1_w, fc1_b,
                                                 fc2_w, fc2_b, vmain);
  // v_injT[b][c][i] = (v_fused @ proj_w + proj_b)^T
  gemm_kernel<NPAD, CCH, CCH, false, true, 2>
      <<<dim3(4, 8, NB), 256, 0, stream>>>(vmain, proj_w, vinjT, proj_b);
  final_kernel<<<32768, 256, 0, stream>>>(x_main, map, vinjT, out);
}

// Round 3
// 542.271 us; speedup vs baseline: 1.9328x; 1.2522x over previous
//
#include <hip/hip_runtime.h>
#include <cstdint>
#include <cstddef>

// Problem constants (fixed by the reference)
#define HW    16384
#define CCH   256
#define WID   128
#define NB    8
#define NSEL  500
#define NPAD  512

// ---------- helpers ----------
__device__ __forceinline__ unsigned key_of(float f) {
  // monotone float->uint map (larger float -> larger uint); logits are finite
  unsigned u = __float_as_uint(f);
  return (u & 0x80000000u) ? ~u : (u | 0x80000000u);
}

// ---------- K1: saliency logits (sigmoid/bias skipped: monotone) ----------
__global__ __launch_bounds__(256) void score_kernel(const float* __restrict__ x,
                                                    const float* __restrict__ w,
                                                    float* __restrict__ logits) {
  __shared__ float ws[CCH];
  int tid = threadIdx.x;
  ws[tid] = w[tid];
  __syncthreads();
  int pix = blockIdx.x * 256 + tid;            // 0 .. B*HW-1
  int b = pix >> 14, p = pix & (HW - 1);
  const float* xp = x + ((size_t)b << 22) + p; // b*C*HW
  float acc = 0.f;
#pragma unroll 16
  for (int c = 0; c < CCH; c++) acc += xp[(size_t)c * HW] * ws[c];
  logits[pix] = acc;
}

// ---------- K2: per-batch top-500, 1024 threads, keys in registers ----------
__global__ __launch_bounds__(1024) void topk_kernel(const float* __restrict__ logits,
                                                    int* __restrict__ idx_out,
                                                    int* __restrict__ map) {
  int b = blockIdx.x, tid = threadIdx.x;
  const float* lg = logits + (size_t)b * HW;
  __shared__ unsigned hist[256];
  __shared__ unsigned sscan[1024];
  __shared__ unsigned bc_prefix;
  __shared__ int bc_want;
  __shared__ int cnt;

  // each thread owns 16 CONSECUTIVE indices [tid*16, tid*16+16) in registers
  unsigned kreg[16];
#pragma unroll
  for (int j = 0; j < 4; j++) {
    float4 v = *(const float4*)&lg[tid * 16 + j * 4];
    kreg[4 * j + 0] = key_of(v.x);
    kreg[4 * j + 1] = key_of(v.y);
    kreg[4 * j + 2] = key_of(v.z);
    kreg[4 * j + 3] = key_of(v.w);
  }
  for (int p = tid; p < HW; p += 1024) map[(size_t)b * HW + p] = -1;

  unsigned prefix = 0;
  int want = NSEL;
  for (int shift = 24; shift >= 0; shift -= 8) {
    if (tid < 256) hist[tid] = 0;
    __syncthreads();
#pragma unroll
    for (int j = 0; j < 16; j++) {
      unsigned u = kreg[j];
      bool m = (shift == 24) || ((u >> (shift + 8)) == (prefix >> (shift + 8)));
      if (m) atomicAdd(&hist[(u >> shift) & 255u], 1u);
    }
    __syncthreads();
    // parallel suffix-sum over 256 bins: sscan[d] = sum_{j>=d} hist[j]
    unsigned h = (tid < 256) ? hist[tid] : 0u;
    if (tid < 256) sscan[tid] = h;
    __syncthreads();
    for (int o = 1; o < 256; o <<= 1) {
      unsigned v = (tid < 256 && tid + o < 256) ? sscan[tid + o] : 0u;
      __syncthreads();
      if (tid < 256) sscan[tid] += v;
      __syncthreads();
    }
    if (tid < 256) {
      unsigned above = sscan[tid] - h;  // count strictly above this bin
      if ((int)sscan[tid] >= want && (int)above < want) {  // exactly one tid
        bc_prefix = prefix | ((unsigned)tid << shift);
        bc_want = want - (int)above;
      }
    }
    __syncthreads();
    prefix = bc_prefix;
    want = bc_want;
    __syncthreads();
  }
  unsigned thr = prefix;  // exact key of boundary element; take `want` ties by lowest index

  int local = 0;
#pragma unroll
  for (int j = 0; j < 16; j++) local += (kreg[j] == thr) ? 1 : 0;
  sscan[tid] = (unsigned)local;
  if (tid == 0) cnt = 0;
  __syncthreads();
  for (int o = 1; o < 1024; o <<= 1) {  // Hillis-Steele inclusive scan
    unsigned v = (tid >= o) ? sscan[tid - o] : 0u;
    __syncthreads();
    sscan[tid] += v;
    __syncthreads();
  }
  int rank = (int)sscan[tid] - local;
#pragma unroll
  for (int j = 0; j < 16; j++) {
    unsigned u = kreg[j];
    bool take = (u > thr);
    if (u == thr) { if (rank < want) take = true; rank++; }
    if (take) {
      int s = atomicAdd(&cnt, 1);
      int p = tid * 16 + j;
      idx_out[b * NPAD + s] = p;
      map[(size_t)b * HW + p] = s;
    }
  }
}

// ---------- shared patch-weight computation ----------
__device__ __forceinline__ void patch_weights(int p, int* xc, int* yc, float* wx, float* wy) {
  int iy = p >> 7, ix = p & (WID - 1);
#pragma unroll
  for (int d = 0; d < 7; d++) {
    int t = ix + d - 3;
    bool in = (t >= 0) && (t < WID);
    xc[d] = in ? t : (t < 0 ? 0 : WID - 1);
    wx[d] = in ? 1.f : 0.5f;
    t = iy + d - 3;
    in = (t >= 0) && (t < WID);
    yc[d] = in ? t : (t < 0 ? 0 : WID - 1);
    wy[d] = in ? 1.f : 0.5f;
  }
}

// ---------- K3: plane-in-LDS gather. grid (C, B, 2feat); writes [b][c][i] ----------
__global__ __launch_bounds__(512) void gather_plane_kernel(const float* __restrict__ xm,
                                                           const float* __restrict__ xa,
                                                           const int* __restrict__ idx,
                                                           float* __restrict__ vmainT,
                                                           float* __restrict__ vauxT) {
  extern __shared__ float plane[];  // HW floats = 64 KB
  int c = blockIdx.x, b = blockIdx.y, z = blockIdx.z;
  int tid = threadIdx.x;
  const float* src = (z == 0 ? xm : xa) + ((size_t)(b * CCH + c)) * HW;
  float* dst = (z == 0 ? vmainT : vauxT) + (((size_t)(b * CCH + c)) << 9);
#pragma unroll
  for (int j = 0; j < 8; j++) {
    int p4 = tid + j * 512;
    *(float4*)&plane[p4 * 4] = *(const float4*)&src[p4 * 4];
  }
  __syncthreads();
  if (tid < NSEL) {
    int p = idx[b * NPAD + tid];
    float wx[7], wy[7];
    int xc[7], yc[7];
    patch_weights(p, xc, yc, wx, wy);
    float s = 0.f, mx = -INFINITY;
#pragma unroll
    for (int dy = 0; dy < 7; dy++) {
      int rb = yc[dy] * WID;
      float wyd = wy[dy];
#pragma unroll
      for (int dx = 0; dx < 7; dx++) {
        float v = plane[rb + xc[dx]] * (wyd * wx[dx]);
        s += v;
        mx = fmaxf(mx, v);
      }
    }
    dst[tid] = 0.5f * (s * (1.f / 49.f) + mx);
  }
}

// ---------- tiled fp32 GEMM: C[b] = A[b](MxK) * B(KxN) ----------
// AT: A stored K-major (KxM). BT: B stored transposed (NxK). BSHARED: B not batched.
// EPI 0: plain store; 1: *0.0625; 2: +bias[col], store transposed [b][N][M]
template <int M, int N, int K, bool AT, bool BT, bool BSHARED, int EPI>
__global__ __launch_bounds__(256) void gemm_kernel(const float* __restrict__ A,
                                                   const float* __restrict__ B,
                                                   float* __restrict__ C,
                                                   const float* __restrict__ bias) {
  constexpr int BM = 64, BN = 64, BK = 16;
  __shared__ float As[BM][BK + 1];
  __shared__ float Bs[BK][BN + 1];
  int tid = threadIdx.x;
  int bx = blockIdx.x, by = blockIdx.y, b = blockIdx.z;
  const float* Ab = A + (size_t)b * M * K;
  const float* Bb = BSHARED ? B : (B + (size_t)b * ((size_t)K * N));
  int tx = tid & 15, ty = tid >> 4;
  float acc[4][4] = {};
  int ar = tid >> 2, ac4 = (tid & 3) * 4;
  int br = tid >> 4, bc4 = (tid & 15) * 4;

  for (int k0 = 0; k0 < K; k0 += BK) {
    if (!AT) {
      const float4 av = *(const float4*)&Ab[(size_t)(by * BM + ar) * K + k0 + ac4];
      As[ar][ac4 + 0] = av.x; As[ar][ac4 + 1] = av.y;
      As[ar][ac4 + 2] = av.z; As[ar][ac4 + 3] = av.w;
    } else {
      // A is K x M: row k0+kr, cols by*BM + mc .. +3 (coalesced)
      int kr = tid >> 4, mc = (tid & 15) * 4;
      const float4 av = *(const float4*)&Ab[(size_t)(k0 + kr) * M + by * BM + mc];
      As[mc + 0][kr] = av.x; As[mc + 1][kr] = av.y;
      As[mc + 2][kr] = av.z; As[mc + 3][kr] = av.w;
    }
    if (!BT) {
      const float4 bv = *(const float4*)&Bb[(size_t)(k0 + br) * N + bx * BN + bc4];
      Bs[br][bc4 + 0] = bv.x; Bs[br][bc4 + 1] = bv.y;
      Bs[br][bc4 + 2] = bv.z; Bs[br][bc4 + 3] = bv.w;
    } else {
      const float4 bv = *(const float4*)&Bb[(size_t)(bx * BN + ar) * K + k0 + ac4];
      Bs[ac4 + 0][ar] = bv.x; Bs[ac4 + 1][ar] = bv.y;
      Bs[ac4 + 2][ar] = bv.z; Bs[ac4 + 3][ar] = bv.w;
    }
    __syncthreads();
#pragma unroll
    for (int kk = 0; kk < BK; kk++) {
      float a[4], bb[4];
#pragma unroll
      for (int r = 0; r < 4; r++) a[r] = As[ty * 4 + r][kk];
#pragma unroll
      for (int s = 0; s < 4; s++) bb[s] = Bs[kk][tx * 4 + s];
#pragma unroll
      for (int r = 0; r < 4; r++)
#pragma unroll
        for (int s = 0; s < 4; s++) acc[r][s] += a[r] * bb[s];
    }
    __syncthreads();
  }
  if (EPI == 2) {
#pragma unroll
    for (int s = 0; s < 4; s++) {
      int col = bx * BN + tx * 4 + s;
      float bv = bias[col];
#pragma unroll
      for (int r = 0; r < 4; r++) {
        int row = by * BM + ty * 4 + r;
        C[((size_t)b * N + col) * M + row] = acc[r][s] + bv;
      }
    }
  } else {
    float scale = (EPI == 1) ? 0.0625f : 1.f;  // 1/sqrt(256)
#pragma unroll
    for (int r = 0; r < 4; r++) {
      int row = by * BM + ty * 4 + r;
#pragma unroll
      for (int s = 0; s < 4; s++) {
        int col = bx * BN + tx * 4 + s;
        C[((size_t)b * M + row) * N + col] = acc[r][s] * scale;
      }
    }
  }
}

// ---------- softmax over j (masked to j<NSEL), in place ----------
__global__ __launch_bounds__(256) void softmax_kernel(float* __restrict__ sim) {
  int i = blockIdx.x, b = blockIdx.y, tid = threadIdx.x;
  float* row = sim + ((size_t)b * NPAD + i) * NPAD;
  float v0 = (tid < NSEL) ? row[tid] : -INFINITY;
  int j1 = tid + 256;
  float v1 = (j1 < NSEL) ? row[j1] : -INFINITY;
  float m = fmaxf(v0, v1);
  for (int o = 32; o; o >>= 1) m = fmaxf(m, __shfl_down(m, o));
  __shared__ float red[4];
  __shared__ float bm, bs;
  int wave = tid >> 6, lane = tid & 63;
  if (lane == 0) red[wave] = m;
  __syncthreads();
  if (tid == 0) bm = fmaxf(fmaxf(red[0], red[1]), fmaxf(red[2], red[3]));
  __syncthreads();
  m = bm;
  float e0 = (tid < NSEL) ? expf(v0 - m) : 0.f;
  float e1 = (j1 < NSEL) ? expf(v1 - m) : 0.f;
  float s = e0 + e1;
  for (int o = 32; o; o >>= 1) s += __shfl_down(s, o);
  if (lane == 0) red[wave] = s;
  __syncthreads();
  if (tid == 0) bs = 1.f / (red[0] + red[1] + red[2] + red[3]);
  __syncthreads();
  row[tid] = e0 * bs;
  row[j1] = e1 * bs;
}

// ---------- gated-fusion MLP: vfused = vm + gate*(vm - vhat) ----------
// vm from channel-major vmainT[b][c][i]; vhat row-major [b][i][c]
__global__ __launch_bounds__(256) void mlp_kernel(const float* __restrict__ vmainT,
                                                  const float* __restrict__ vhat,
                                                  const float* __restrict__ fc1w,
                                                  const float* __restrict__ fc1b,
                                                  const float* __restrict__ fc2w,
                                                  const float* __restrict__ fc2b,
                                                  float* __restrict__ vfused) {
  int i = blockIdx.x, b = blockIdx.y, c = threadIdx.x;
  size_t base = ((size_t)b * NPAD + i) * CCH + c;
  float vm = vmainT[(((size_t)(b * CCH + c)) << 9) + i];
  float vh = vhat[base], vd = vm - vh;
  const float* w0 = fc1w + (size_t)c * 16;
  const float* w1 = fc1w + (size_t)(256 + c) * 16;
  const float* w2 = fc1w + (size_t)(512 + c) * 16;
  float ph[16];
#pragma unroll
  for (int k = 0; k < 16; k++) ph[k] = vm * w0[k] + vh * w1[k] + vd * w2[k];
#pragma unroll
  for (int o = 32; o; o >>= 1)
#pragma unroll
    for (int k = 0; k < 16; k++) ph[k] += __shfl_down(ph[k], o);
  __shared__ float red[4][16];
  __shared__ float hsh[16];
  int wave = c >> 6, lane = c & 63;
  if (lane == 0)
#pragma unroll
    for (int k = 0; k < 16; k++) red[wave][k] = ph[k];
  __syncthreads();
  if (c < 16) {
    float s = red[0][c] + red[1][c] + red[2][c] + red[3][c] + fc1b[c];
    hsh[c] = fmaxf(s, 0.f);
  }
  __syncthreads();
  float g = fc2b[c];
#pragma unroll
  for (int k = 0; k < 16; k++) g += hsh[k] * fc2w[k * 256 + c];
  g = 1.f / (1.f + expf(-g));
  vfused[base] = vm + g * vd;
}

// ---------- K5: out = x_main + dense-map lookup of v_injT ----------
__global__ __launch_bounds__(256) void final_kernel(const float* __restrict__ x,
                                                    const int* __restrict__ map,
                                                    const float* __restrict__ vinjT,
                                                    float* __restrict__ out) {
  int gid = blockIdx.x * 256 + threadIdx.x;  // B*C*HW/4 threads
  int p4 = gid & 4095;
  int c = (gid >> 12) & 255;
  int b = gid >> 20;
  size_t xoff = (((size_t)(b * 256 + c)) << 14) + ((size_t)p4 << 2);
  float4 xv = *(const float4*)(x + xoff);
  const int4 mv = *(const int4*)(map + ((size_t)b << 14) + (p4 << 2));
  const float* vt = vinjT + ((size_t)(b * 256 + c) << 9);
  if (mv.x >= 0) xv.x += vt[mv.x];
  if (mv.y >= 0) xv.y += vt[mv.y];
  if (mv.z >= 0) xv.z += vt[mv.z];
  if (mv.w >= 0) xv.w += vt[mv.w];
  *(float4*)(out + xoff) = xv;
}

extern "C" void kernel_launch(void* const* d_in, const int* in_sizes, int n_in,
                              void* d_out, int out_size, void* d_ws, size_t ws_size,
                              hipStream_t stream) {
  const float* x_main   = (const float*)d_in[0];
  const float* x_aux    = (const float*)d_in[1];
  const float* scorer_w = (const float*)d_in[2];
  // d_in[3] scorer_b: constant shift, irrelevant to top-k set -> unused
  const float* fc1_w = (const float*)d_in[4];
  const float* fc1_b = (const float*)d_in[5];
  const float* fc2_w = (const float*)d_in[6];
  const float* fc2_b = (const float*)d_in[7];
  const float* proj_w = (const float*)d_in[8];
  const float* proj_b = (const float*)d_in[9];
  // d_in[10] n == 500 (fixed)
  (void)in_sizes; (void)n_in; (void)out_size; (void)ws_size;

  float* ws = (float*)d_ws;
  // workspace layout (floats), ~26 MB total
  float* logits = ws;                      // 131072
  int*   idx    = (int*)(ws + 131072);     // 4096
  int*   map    = (int*)(ws + 135168);     // 131072
  float* vmainT = ws + 266240;             // 1048576  [b][c][i]
  float* vauxT  = ws + 1314816;            // 1048576  [b][c][i]
  float* vhat   = ws + 2363392;            // 1048576  [b][i][c] (v_injT reuses this)
  float* vfused = ws + 3411968;            // 1048576  [b][i][c]
  float* sim    = ws + 4460544;            // 2097152  [b][i][j]
  float* vinjT  = vhat;
  float* out = (float*)d_out;

  score_kernel<<<512, 256, 0, stream>>>(x_main, scorer_w, logits);
  topk_kernel<<<NB, 1024, 0, stream>>>(logits, idx, map);
  gather_plane_kernel<<<dim3(CCH, NB, 2), 512, HW * sizeof(float), stream>>>(
      x_main, x_aux, idx, vmainT, vauxT);
  // sim[b][i][j] = sum_c vmainT[b][c][i] * vauxT[b][c][j] / 16   (TN gemm)
  gemm_kernel<NPAD, NPAD, CCH, true, false, false, 1>
      <<<dim3(8, 8, NB), 256, 0, stream>>>(vmainT, vauxT, sim, nullptr);
  softmax_kernel<<<dim3(NPAD, NB), 256, 0, stream>>>(sim);
  // v_hat[b][i][c] = sum_j attn[b][i][j] * vauxT[b][c][j]   (B transposed)
  gemm_kernel<NPAD, CCH, NPAD, false, true, false, 0>
      <<<dim3(4, 8, NB), 256, 0, stream>>>(sim, vauxT, vhat, nullptr);
  mlp_kernel<<<dim3(NPAD, NB), 256, 0, stream>>>(vmainT, vhat, fc1_w, fc1_b,
                                                 fc2_w, fc2_b, vfused);
  // v_injT[b][c][i] = (v_fused @ proj_w + proj_b)^T
  gemm_kernel<NPAD, CCH, CCH, false, false, true, 2>
      <<<dim3(4, 8, NB), 256, 0, stream>>>(vfused, proj_w, vinjT, proj_b);
  final_kernel<<<32768, 256, 0, stream>>>(x_main, map, vinjT, out);
}